// Round 13
// baseline (76.390 us; speedup 1.0000x reference)
//
#include <hip/hip_runtime.h>

// out[b,c,l] = sum_r x[b,r,l] * weight[idx[b,l], r, c] + bias[idx[b,l], c]
//   x:       (4, 256, 32, 32) fp32   flat (b*256 + r)*1024 + l
//   indexes: (4096,) int             j in [0,8)
//   weight:  (8, 256, 256) fp32     (j*256 + r)*256 + c
//   bias:    (8, 256) fp32
//   out:     (4, 256, 32, 32) fp32  (b*256 + c)*1024 + l
//
// R13: R12 (dense redundant-j MFMA, k-pair-packed LDS, double-buffered
// phases) with phase size halved to K=32: LDS 67.6 -> 33.8 KB and
// prefetch registers 64 -> 32 VGPRs, lifting occupancy from 2 to 3
// blocks/CU (12 waves) so staging latency / LDS pipe / MFMA overlap
// across more independent waves. 8 phases, one barrier each.
//
// Fragment layouts verified on HW in R8 (16x16x32 bf16):
//   A[m=lane&15][k=quad*8+i], B[k=quad*8+i][n=lane&15], D[m=quad*4+r][n=lane&15]

#define C_DIM 256
#define KD    256
#define CB    128      // c per block
#define LB    128      // l per block
#define KP    32       // K per phase
#define NPH   8        // phases
#define LDP   132      // LDS row stride (dwords): (row*132+c)%32 = (row*4+c)%32

typedef __attribute__((ext_vector_type(8))) short bf16x8;
typedef __attribute__((ext_vector_type(4))) float f32x4;

// pack two floats into one dword of bf16 (round-half-up, 0.5-ulp like RNE)
__device__ inline unsigned pk2(float a, float b) {
    union { float f; unsigned u; } x, y; x.f = a; y.f = b;
    return ((x.u + 0x8000u) >> 16) | ((y.u + 0x8000u) & 0xFFFF0000u);
}

__global__ __launch_bounds__(256, 3) void fused_mfma_kernel(
    const float* __restrict__ x,
    const int*   __restrict__ idx,
    const float* __restrict__ weight,
    const float* __restrict__ bias,
    float*       __restrict__ out)
{
    const int t    = threadIdx.x;
    const int lane = t & 63;
    const int wav  = t >> 6;
    const int quad = lane >> 4;
    const int li   = lane & 15;

    const int j    = blockIdx.z;
    const int cb0  = blockIdx.x * CB;
    const int lg0b = blockIdx.y * LB;
    const int b    = lg0b >> 10;          // 128-tiles never straddle b
    const int l0b  = lg0b & 1023;

    __shared__ unsigned Asl[2][16 * LDP]; // [buf][k2_local][c]  (32 k/phase)
    __shared__ unsigned Bsl[2][16 * LDP]; // [buf][k2_local][l]

    const int c_locb = (wav & 1) * 64;    // wave's c-half within block
    const int l_locb = (wav >> 1) * 64;   // wave's l-half

    const float* __restrict__ wbase = weight + j * (KD * C_DIM) + cb0;
    const float* __restrict__ xbase = x + (b << 18) + l0b;

    const int sc4  = (t & 31) * 4;        // staging column (c or l), float4
    const int srow = t >> 5;              // 0..7: k-pair row within iter group

    // epilogue predicate loads issued early (overlap with whole main loop)
    bool keep[4];
    int  lgv[4];
    #pragma unroll
    for (int nt = 0; nt < 4; ++nt) {
        lgv[nt]  = lg0b + l_locb + nt * 16 + li;
        keep[nt] = (idx[lgv[nt]] == j);
    }

    f32x4 acc[4][4];
    #pragma unroll
    for (int mt = 0; mt < 4; ++mt)
        #pragma unroll
        for (int nt = 0; nt < 4; ++nt)
            acc[mt][nt] = (f32x4){0.f, 0.f, 0.f, 0.f};

    // ---- prologue: load + stage phase 0 into buffer 0 ----
    float4 a0[2], a1[2], b0[2], b1[2];
    #pragma unroll
    for (int i = 0; i < 2; ++i) {
        const int kp = i * 8 + srow;      // 0..15
        const int k  = kp * 2;
        a0[i] = *(const float4*)(wbase + k * C_DIM + sc4);
        a1[i] = *(const float4*)(wbase + (k + 1) * C_DIM + sc4);
        b0[i] = *(const float4*)(xbase + (k << 10) + sc4);
        b1[i] = *(const float4*)(xbase + ((k + 1) << 10) + sc4);
    }
    #pragma unroll
    for (int i = 0; i < 2; ++i) {
        const int kp = i * 8 + srow;
        uint4 pa, pb;
        pa.x = pk2(a0[i].x, a1[i].x); pa.y = pk2(a0[i].y, a1[i].y);
        pa.z = pk2(a0[i].z, a1[i].z); pa.w = pk2(a0[i].w, a1[i].w);
        pb.x = pk2(b0[i].x, b1[i].x); pb.y = pk2(b0[i].y, b1[i].y);
        pb.z = pk2(b0[i].z, b1[i].z); pb.w = pk2(b0[i].w, b1[i].w);
        *(uint4*)&Asl[0][kp * LDP + sc4] = pa;
        *(uint4*)&Bsl[0][kp * LDP + sc4] = pb;
    }
    __syncthreads();

    #pragma unroll
    for (int p = 0; p < NPH; ++p) {
        // 1. issue next phase's global loads (in flight across compute+barrier)
        if (p < NPH - 1) {
            const int k0 = (p + 1) * KP;
            #pragma unroll
            for (int i = 0; i < 2; ++i) {
                const int kp = i * 8 + srow;
                const int k  = k0 + kp * 2;
                a0[i] = *(const float4*)(wbase + k * C_DIM + sc4);
                a1[i] = *(const float4*)(wbase + (k + 1) * C_DIM + sc4);
                b0[i] = *(const float4*)(xbase + (k << 10) + sc4);
                b1[i] = *(const float4*)(xbase + ((k + 1) << 10) + sc4);
            }
        }

        // 2. compute one K=32 chunk from buffer p&1
        {
            const unsigned* __restrict__ Ab = Asl[p & 1];
            const unsigned* __restrict__ Bb = Bsl[p & 1];
            const int rbase = quad * 4;
            bf16x8 af[4], bfr[4];
            #pragma unroll
            for (int mt = 0; mt < 4; ++mt) {
                const int cl = c_locb + mt * 16 + li;
                uint4 u;
                u.x = Ab[(rbase + 0) * LDP + cl];
                u.y = Ab[(rbase + 1) * LDP + cl];
                u.z = Ab[(rbase + 2) * LDP + cl];
                u.w = Ab[(rbase + 3) * LDP + cl];
                af[mt] = __builtin_bit_cast(bf16x8, u);
            }
            #pragma unroll
            for (int nt = 0; nt < 4; ++nt) {
                const int ll = l_locb + nt * 16 + li;
                uint4 u;
                u.x = Bb[(rbase + 0) * LDP + ll];
                u.y = Bb[(rbase + 1) * LDP + ll];
                u.z = Bb[(rbase + 2) * LDP + ll];
                u.w = Bb[(rbase + 3) * LDP + ll];
                bfr[nt] = __builtin_bit_cast(bf16x8, u);
            }
            #pragma unroll
            for (int mt = 0; mt < 4; ++mt)
                #pragma unroll
                for (int nt = 0; nt < 4; ++nt)
                    acc[mt][nt] = __builtin_amdgcn_mfma_f32_16x16x32_bf16(
                        af[mt], bfr[nt], acc[mt][nt], 0, 0, 0);
        }

        // 3. pack + write next phase into the alternate buffer, then barrier
        if (p < NPH - 1) {
            const int q = (p + 1) & 1;
            #pragma unroll
            for (int i = 0; i < 2; ++i) {
                const int kp = i * 8 + srow;
                uint4 pa, pb;
                pa.x = pk2(a0[i].x, a1[i].x); pa.y = pk2(a0[i].y, a1[i].y);
                pa.z = pk2(a0[i].z, a1[i].z); pa.w = pk2(a0[i].w, a1[i].w);
                pb.x = pk2(b0[i].x, b1[i].x); pb.y = pk2(b0[i].y, b1[i].y);
                pb.z = pk2(b0[i].z, b1[i].z); pb.w = pk2(b0[i].w, b1[i].w);
                *(uint4*)&Asl[q][kp * LDP + sc4] = pa;
                *(uint4*)&Bsl[q][kp * LDP + sc4] = pb;
            }
            __syncthreads();
        }
    }

    // ---- epilogue: masked scatter to out (b,c,l) ----
    #pragma unroll
    for (int mt = 0; mt < 4; ++mt) {
        const int cb = cb0 + c_locb + mt * 16 + quad * 4;
        const float4 bb = *(const float4*)(bias + j * C_DIM + cb);
        #pragma unroll
        for (int nt = 0; nt < 4; ++nt) {
            if (!keep[nt]) continue;
            float* __restrict__ op = out + (b << 18) + (cb << 10) + (lgv[nt] & 1023);
            op[0 << 10] = acc[mt][nt][0] + bb.x;
            op[1 << 10] = acc[mt][nt][1] + bb.y;
            op[2 << 10] = acc[mt][nt][2] + bb.z;
            op[3 << 10] = acc[mt][nt][3] + bb.w;
        }
    }
}

extern "C" void kernel_launch(void* const* d_in, const int* in_sizes, int n_in,
                              void* d_out, int out_size, void* d_ws, size_t ws_size,
                              hipStream_t stream)
{
    const float* x      = (const float*)d_in[0];
    const int*   idx    = (const int*)  d_in[1];
    const float* weight = (const float*)d_in[2];
    const float* bias   = (const float*)d_in[3];
    float*       out    = (float*)      d_out;

    // grid: (2 c-tiles, 32 l-tiles, 8 j) = 512 blocks; j slowest so the 8
    // j-blocks of a (c,l) tile share an XCD residue -> L2 merges their
    // partial output lines.
    fused_mfma_kernel<<<dim3(2, 32, 8), 256, 0, stream>>>(x, idx, weight, bias, out);
}

// Round 14
// 72.946 us; speedup vs baseline: 1.0472x; 1.0472x over previous
//
#include <hip/hip_runtime.h>

// out[b,c,l] = sum_r x[b,r,l] * weight[idx[b,l], r, c] + bias[idx[b,l], c]
//   x:       (4, 256, 32, 32) fp32   flat (b*256 + r)*1024 + l
//   indexes: (4096,) int             j in [0,8)
//   weight:  (8, 256, 256) fp32     (j*256 + r)*256 + c
//   bias:    (8, 256) fp32
//   out:     (4, 256, 32, 32) fp32  (b*256 + c)*1024 + l
//
// R14 = R12 (measured best, 72.4 us): dense redundant-j MFMA, K=64 phases,
// k-pair-packed dword LDS, double-buffered (loads for phase p+1 in flight
// across compute+barrier of phase p), 2 blocks/CU. Only change vs R12:
// epilogue idx predicate loads hoisted before the main loop.
// R13 (K=32 phases, 3 blocks/CU) regressed to 76.4 — more barriers cost
// more than the extra occupancy bought.
//
// Fragment layouts verified on HW in R8 (16x16x32 bf16):
//   A[m=lane&15][k=quad*8+i], B[k=quad*8+i][n=lane&15], D[m=quad*4+r][n=lane&15]

#define C_DIM 256
#define KD    256
#define CB    128      // c per block
#define LB    128      // l per block
#define LDP   132      // LDS row stride (dwords): (row*132+c)%32 = (row*4+c)%32

typedef __attribute__((ext_vector_type(8))) short bf16x8;
typedef __attribute__((ext_vector_type(4))) float f32x4;

// pack two floats into one dword of bf16 (round-half-up, 0.5-ulp like RNE)
__device__ inline unsigned pk2(float a, float b) {
    union { float f; unsigned u; } x, y; x.f = a; y.f = b;
    return ((x.u + 0x8000u) >> 16) | ((y.u + 0x8000u) & 0xFFFF0000u);
}

__global__ __launch_bounds__(256, 2) void fused_mfma_kernel(
    const float* __restrict__ x,
    const int*   __restrict__ idx,
    const float* __restrict__ weight,
    const float* __restrict__ bias,
    float*       __restrict__ out)
{
    const int t    = threadIdx.x;
    const int lane = t & 63;
    const int wav  = t >> 6;
    const int quad = lane >> 4;
    const int li   = lane & 15;

    const int j    = blockIdx.z;
    const int cb0  = blockIdx.x * CB;
    const int lg0b = blockIdx.y * LB;
    const int b    = lg0b >> 10;          // 128-tiles never straddle b
    const int l0b  = lg0b & 1023;

    __shared__ unsigned Asl[2][32 * LDP]; // [buf][k2_local][c]  (64 k/phase)
    __shared__ unsigned Bsl[2][32 * LDP]; // [buf][k2_local][l]

    const int c_locb = (wav & 1) * 64;    // wave's c-half within block
    const int l_locb = (wav >> 1) * 64;   // wave's l-half

    const float* __restrict__ wbase = weight + j * (KD * C_DIM) + cb0;
    const float* __restrict__ xbase = x + (b << 18) + l0b;

    const int sc4  = (t & 31) * 4;        // staging column (c or l), float4
    const int srow = t >> 5;              // 0..7: pair-row within iter group

    // epilogue predicates issued early — overlap the entire main loop
    bool keep[4];
    int  lgv[4];
    #pragma unroll
    for (int nt = 0; nt < 4; ++nt) {
        lgv[nt]  = lg0b + l_locb + nt * 16 + li;
        keep[nt] = (idx[lgv[nt]] == j);
    }

    f32x4 acc[4][4];
    #pragma unroll
    for (int mt = 0; mt < 4; ++mt)
        #pragma unroll
        for (int nt = 0; nt < 4; ++nt)
            acc[mt][nt] = (f32x4){0.f, 0.f, 0.f, 0.f};

    // ---- prologue: load + stage phase 0 into buffer 0 ----
    float4 a0[4], a1[4], b0[4], b1[4];
    #pragma unroll
    for (int i = 0; i < 4; ++i) {
        const int kp = i * 8 + srow;
        const int k  = kp * 2;
        a0[i] = *(const float4*)(wbase + k * C_DIM + sc4);
        a1[i] = *(const float4*)(wbase + (k + 1) * C_DIM + sc4);
        b0[i] = *(const float4*)(xbase + (k << 10) + sc4);
        b1[i] = *(const float4*)(xbase + ((k + 1) << 10) + sc4);
    }
    #pragma unroll
    for (int i = 0; i < 4; ++i) {
        const int kp = i * 8 + srow;
        uint4 pa, pb;
        pa.x = pk2(a0[i].x, a1[i].x); pa.y = pk2(a0[i].y, a1[i].y);
        pa.z = pk2(a0[i].z, a1[i].z); pa.w = pk2(a0[i].w, a1[i].w);
        pb.x = pk2(b0[i].x, b1[i].x); pb.y = pk2(b0[i].y, b1[i].y);
        pb.z = pk2(b0[i].z, b1[i].z); pb.w = pk2(b0[i].w, b1[i].w);
        *(uint4*)&Asl[0][kp * LDP + sc4] = pa;
        *(uint4*)&Bsl[0][kp * LDP + sc4] = pb;
    }
    __syncthreads();

    #pragma unroll
    for (int p = 0; p < 4; ++p) {
        // 1. issue next phase's global loads (in flight across compute+barrier)
        if (p < 3) {
            const int k0 = (p + 1) * 64;
            #pragma unroll
            for (int i = 0; i < 4; ++i) {
                const int kp = i * 8 + srow;
                const int k  = k0 + kp * 2;
                a0[i] = *(const float4*)(wbase + k * C_DIM + sc4);
                a1[i] = *(const float4*)(wbase + (k + 1) * C_DIM + sc4);
                b0[i] = *(const float4*)(xbase + (k << 10) + sc4);
                b1[i] = *(const float4*)(xbase + ((k + 1) << 10) + sc4);
            }
        }

        // 2. compute 2 chunks of K=32 from buffer p&1
        const unsigned* __restrict__ Ab = Asl[p & 1];
        const unsigned* __restrict__ Bb = Bsl[p & 1];
        #pragma unroll
        for (int h = 0; h < 2; ++h) {
            const int rbase = h * 16 + quad * 4;
            bf16x8 af[4], bfr[4];
            #pragma unroll
            for (int mt = 0; mt < 4; ++mt) {
                const int cl = c_locb + mt * 16 + li;
                uint4 u;
                u.x = Ab[(rbase + 0) * LDP + cl];
                u.y = Ab[(rbase + 1) * LDP + cl];
                u.z = Ab[(rbase + 2) * LDP + cl];
                u.w = Ab[(rbase + 3) * LDP + cl];
                af[mt] = __builtin_bit_cast(bf16x8, u);
            }
            #pragma unroll
            for (int nt = 0; nt < 4; ++nt) {
                const int ll = l_locb + nt * 16 + li;
                uint4 u;
                u.x = Bb[(rbase + 0) * LDP + ll];
                u.y = Bb[(rbase + 1) * LDP + ll];
                u.z = Bb[(rbase + 2) * LDP + ll];
                u.w = Bb[(rbase + 3) * LDP + ll];
                bfr[nt] = __builtin_bit_cast(bf16x8, u);
            }
            #pragma unroll
            for (int mt = 0; mt < 4; ++mt)
                #pragma unroll
                for (int nt = 0; nt < 4; ++nt)
                    acc[mt][nt] = __builtin_amdgcn_mfma_f32_16x16x32_bf16(
                        af[mt], bfr[nt], acc[mt][nt], 0, 0, 0);
        }

        // 3. pack + write next phase into the alternate buffer, then barrier
        if (p < 3) {
            const int q = (p + 1) & 1;
            #pragma unroll
            for (int i = 0; i < 4; ++i) {
                const int kp = i * 8 + srow;
                uint4 pa, pb;
                pa.x = pk2(a0[i].x, a1[i].x); pa.y = pk2(a0[i].y, a1[i].y);
                pa.z = pk2(a0[i].z, a1[i].z); pa.w = pk2(a0[i].w, a1[i].w);
                pb.x = pk2(b0[i].x, b1[i].x); pb.y = pk2(b0[i].y, b1[i].y);
                pb.z = pk2(b0[i].z, b1[i].z); pb.w = pk2(b0[i].w, b1[i].w);
                *(uint4*)&Asl[q][kp * LDP + sc4] = pa;
                *(uint4*)&Bsl[q][kp * LDP + sc4] = pb;
            }
            __syncthreads();
        }
    }

    // ---- epilogue: masked scatter to out (b,c,l) ----
    #pragma unroll
    for (int mt = 0; mt < 4; ++mt) {
        const int cb = cb0 + c_locb + mt * 16 + quad * 4;
        const float4 bb = *(const float4*)(bias + j * C_DIM + cb);
        #pragma unroll
        for (int nt = 0; nt < 4; ++nt) {
            if (!keep[nt]) continue;
            float* __restrict__ op = out + (b << 18) + (cb << 10) + (lgv[nt] & 1023);
            op[0 << 10] = acc[mt][nt][0] + bb.x;
            op[1 << 10] = acc[mt][nt][1] + bb.y;
            op[2 << 10] = acc[mt][nt][2] + bb.z;
            op[3 << 10] = acc[mt][nt][3] + bb.w;
        }
    }
}

extern "C" void kernel_launch(void* const* d_in, const int* in_sizes, int n_in,
                              void* d_out, int out_size, void* d_ws, size_t ws_size,
                              hipStream_t stream)
{
    const float* x      = (const float*)d_in[0];
    const int*   idx    = (const int*)  d_in[1];
    const float* weight = (const float*)d_in[2];
    const float* bias   = (const float*)d_in[3];
    float*       out    = (float*)      d_out;

    // grid: (2 c-tiles, 32 l-tiles, 8 j) = 512 blocks = 2 blocks/CU; j is
    // slowest so the 8 j-blocks of a (c,l) tile share an XCD residue ->
    // L2 merges their partial output lines.
    fused_mfma_kernel<<<dim3(2, 32, 8), 256, 0, stream>>>(x, idx, weight, bias, out);
}